// Round 10
// baseline (73.744 us; speedup 1.0000x reference)
//
#include <hip/hip_runtime.h>

#define NB 32
#define TT 512
#define UU 100
#define UM 101   // U+1
#define VV 4096
#define NEG (-1e30f)
#define PW 16            // ring depth (diagonals per ring)
#define WINB 32          // diagonals per build block
#define NWIN 22          // covers d = 1 .. 704
#define DST 720          // stream d-stride per n (dp reads to dend+95 <= 706)
#define L2E 1.4426950408889634f
#define LN2 0.6931471805599453f

__device__ __forceinline__ float vexp2(float x){ float r; asm("v_exp_f32 %0, %1" : "=v"(r) : "v"(x)); return r; }
__device__ __forceinline__ float vlog2(float x){ float r; asm("v_log_f32 %0, %1" : "=v"(r) : "v"(x)); return r; }

// logaddexp in log2 domain
__device__ __forceinline__ float lae2(float a, float b) {
    float m  = fmaxf(a, b);
    float nd = fminf(a, b) - m;          // = -|a-b|
    return m + vlog2(1.0f + vexp2(nd));
}

// Full-chip gather: block (w, n) fills diagonals d = w*32+1 .. w*32+32 of the
// emit stream st[n][d][u]. Guarded exec-masked loads with deferred uses
// (16 independent misses in flight per lane), coalesced stores.
__global__ __launch_bounds__(256) void build_k(
        const float* __restrict__ enc, const float* __restrict__ dec,
        const int* __restrict__ tgt, const int* __restrict__ ilen,
        const int* __restrict__ tlen, float* __restrict__ st) {
    int w = blockIdx.x, n = blockIdx.y;
    int tid = threadIdx.x;
    int tin = ilen[n], tg = tlen[n];
    if (w * WINB + 1 > tin + tg) return;   // dp reads past dend are capture-safe junk
    __shared__ int   tgtL[UU];
    __shared__ float dvxL[UU];
    if (tid < UU) {
        int y = tgt[n * UU + tid];
        tgtL[tid] = y;
        dvxL[tid] = dec[((size_t)n * UM + tid) * VV + y] * L2E;
    }
    __syncthreads();
    const float* encn = enc + (size_t)n * TT * VV;

    float ev[16];
    // phase 1: issue all loads, no uses (MLP = 16 per lane)
#pragma unroll
    for (int it = 0; it < 16; ++it) {
        int idx = tid + it * 256;            // 0..4095
        int dm = idx >> 7, u = idx & 127;
        int d = w * WINB + 1 + dm;
        int t = d - u;
        bool ok = (u >= 1) & (u <= tg) & (t >= 0) & (t < tin);
        ev[it] = NEG;
        if (ok) ev[it] = encn[(size_t)t * VV + tgtL[u - 1]];   // exec-masked load
    }
    // phase 2: select + coalesced store
#pragma unroll
    for (int it = 0; it < 16; ++it) {
        int idx = tid + it * 256;
        int dm = idx >> 7, u = idx & 127;
        int d = w * WINB + 1 + dm;
        int t = d - u;
        bool ok = (u >= 1) & (u <= tg) & (t >= 0) & (t < tin);
        int uc = max(u, 1);
        float e = ok ? fmaf(ev[it], L2E, dvxL[uc - 1]) : NEG;
        st[((size_t)n * DST + d) * 128 + u] = e;
    }
}

// wavefront DP: lane L owns u=2L (a0) and u=2L+1 (a1). Emit edges from the
// diagonal-major global stream; blank edges rebuilt from NEG-padded LDS blkL.
// THREE 16-diagonal register rings: REFILL(X, d+48) right after STEPS(X, d)
// -> issue-to-consume distance = 32 diagonals (~1000 cy), covering cross-XCD
// L3/HBM latency.
__global__ __launch_bounds__(256, 1) void dp_k(
        const float* __restrict__ enc, const float* __restrict__ dec,
        const int* __restrict__ ilen, const int* __restrict__ tlen,
        const float* __restrict__ st, float* __restrict__ out) {
    int n = blockIdx.x;
    int tid = threadIdx.x;
    __shared__ float blkL[864];   // blkL[128+t] = enc[n][t][0]*L2E, NEG pads
    const float* encn = enc + (size_t)n * TT * VV;
    for (int i = tid; i < 864; i += 256)
        blkL[i] = (i >= 128 && i < 128 + TT) ? encn[(size_t)(i - 128) * VV] * L2E : NEG;
    __syncthreads();
    if (tid >= 64) return;
    int lane = tid;

    int tin = ilen[n], tg = tlen[n];
    int dend = tin - 1 + tg;
    const float* decn = dec + (size_t)n * UM * VV;
    float bd0 = decn[(size_t)min(2 * lane, UM - 1) * VV] * L2E;
    float bd1 = decn[(size_t)min(2 * lane + 1, UM - 1) * VV] * L2E;
    const float* sp = st + (size_t)n * DST * 128 + 2 * lane;
    int ib0 = 127 - 2 * lane;     // blkL idx of slot0's blk[t-1] is ib0 + d
    bool cap0 = (2 * lane == tg), cap1 = (2 * lane + 1 == tg);
    bool fx16 = (lane == 16), fx32 = (lane == 32), fx48 = (lane == 48);
    float a0 = (lane == 0) ? 0.0f : NEG;   // alpha[0][0] = 0 at d=0
    float a1 = NEG;
    float res = NEG;

    float Ae0[PW], Ae1[PW], Ab0[PW], Ab1[PW];
    float Be0[PW], Be1[PW], Bb0[PW], Bb1[PW];
    float Ce0[PW], Ce1[PW], Cb0[PW], Cb1[PW];

    auto REFILL = [&](float (&Re0)[PW], float (&Re1)[PW],
                      float (&Rb0)[PW], float (&Rb1)[PW], int d0) {
#pragma unroll
        for (int k = 0; k < PW; ++k) {
            int d = d0 + k;
            float2 ev = *(const float2*)(sp + (size_t)d * 128);
            Re0[k] = ev.x; Re1[k] = ev.y;
            Rb0[k] = blkL[ib0 + d] + bd0;
            Rb1[k] = blkL[ib0 + d - 1] + bd1;
        }
        __builtin_amdgcn_sched_barrier(0);
    };

    auto STEPS = [&](float (&Re0)[PW], float (&Re1)[PW],
                     float (&Rb0)[PW], float (&Rb1)[PW], int d0) {
#pragma unroll
        for (int k = 0; k < PW; ++k) {
            int dd = d0 + k;
            // left neighbor of u=2L is lane L-1's a1: DPP row_shr:1 + seam fixups
            int sh = __builtin_amdgcn_update_dpp(__float_as_int(NEG), __float_as_int(a1),
                                                 0x111, 0xF, 0xF, false);   // row_shr:1
            float s15 = __int_as_float(__builtin_amdgcn_readlane(__float_as_int(a1), 15));
            float s31 = __int_as_float(__builtin_amdgcn_readlane(__float_as_int(a1), 31));
            float s47 = __int_as_float(__builtin_amdgcn_readlane(__float_as_int(a1), 47));
            float l0 = __int_as_float(sh);
            l0 = fx16 ? s15 : l0;
            l0 = fx32 ? s31 : l0;
            l0 = fx48 ? s47 : l0;
            float bt0 = a0 + Rb0[k], et0 = l0 + Re0[k];
            float bt1 = a1 + Rb1[k], et1 = a0 + Re1[k];   // old a0: same-lane left neighbor
            a0 = lae2(bt0, et0);
            a1 = lae2(bt1, et1);
            if (dd == dend) { if (cap0) res = a0; if (cap1) res = a1; }
        }
        __builtin_amdgcn_sched_barrier(0);
    };

    REFILL(Ae0, Ae1, Ab0, Ab1, 1);
    REFILL(Be0, Be1, Bb0, Bb1, 1 + PW);
    REFILL(Ce0, Ce1, Cb0, Cb1, 1 + 2 * PW);
    for (int d0 = 1; d0 <= dend; d0 += 3 * PW) {
        STEPS(Ae0, Ae1, Ab0, Ab1, d0);          REFILL(Ae0, Ae1, Ab0, Ab1, d0 + 3 * PW);
        STEPS(Be0, Be1, Bb0, Bb1, d0 + PW);     REFILL(Be0, Be1, Bb0, Bb1, d0 + 4 * PW);
        STEPS(Ce0, Ce1, Cb0, Cb1, d0 + 2 * PW); REFILL(Ce0, Ce1, Cb0, Cb1, d0 + 5 * PW);
        // max d read = d0 + 5*PW + 15 <= dend + 95 <= 706 < DST. Rows past
        // tin+tg hold junk (finite poison / stale) — consumed only after res
        // is latched at dd == dend, so capture-safe.
    }

    if (cap0 | cap1) {
        float fin  = blkL[128 + tin - 1];
        float bdtg = decn[(size_t)tg * VV] * L2E;
        out[n] = (res + fin + bdtg) * LN2;
    }
}

extern "C" void kernel_launch(void* const* d_in, const int* in_sizes, int n_in,
                              void* d_out, int out_size, void* d_ws, size_t ws_size,
                              hipStream_t hs) {
    const float* enc  = (const float*)d_in[0];
    const float* dec  = (const float*)d_in[1];
    const int*   tgt  = (const int*)d_in[2];
    const int*   ilen = (const int*)d_in[3];
    const int*   tlen = (const int*)d_in[4];
    float* out = (float*)d_out;
    float* st  = (float*)d_ws;   // NB*DST*128 floats = 11.8 MB

    hipLaunchKernelGGL(build_k, dim3(NWIN, NB), dim3(256), 0, hs,
                       enc, dec, tgt, ilen, tlen, st);
    hipLaunchKernelGGL(dp_k, dim3(NB), dim3(256), 0, hs,
                       enc, dec, ilen, tlen, st, out);
}